// Round 3
// baseline (162.076 us; speedup 1.0000x reference)
//
#include <hip/hip_runtime.h>
#include <math.h>

#define N_NODES 50000
#define N_EDGES 1600000
#define IN_SIZE 128
#define HD 128          // NUM_HEADS * OUT_SIZE
#define NUM_HEADS 4
#define OUT_SIZE 32
#define STRIPS (N_NODES / 16)        // 3125 16-row strips
#define STRIPS_PER_WAVE 3
#define PROJ_WAVES ((STRIPS + STRIPS_PER_WAVE - 1) / STRIPS_PER_WAVE)   // 1042
#define PROJ_BLOCKS ((PROJ_WAVES + 3) / 4)                               // 261
#define OFF_BLOCKS ((N_NODES + 1 + 255) / 256)                           // 196

// 1/sqrt(32) * log2(e): base-2 softmax (exact reformulation)
#define SCALE2 0.25503486f

typedef _Float16 half8 __attribute__((ext_vector_type(8)));
typedef _Float16 half2v __attribute__((ext_vector_type(2)));
typedef __attribute__((ext_vector_type(4))) float floatx4;

static __device__ __forceinline__ half2v pk_f16(float a, float b) {
#if __has_builtin(__builtin_amdgcn_cvt_pkrtz)
    auto r = __builtin_amdgcn_cvt_pkrtz(a, b);         // v_cvt_pkrtz_f16_f32
    union { decltype(r) i; half2v o; } u;
    u.i = r;
    return u.o;
#else
    half2v r; r.x = (_Float16)a; r.y = (_Float16)b; return r;
#endif
}

static __device__ __forceinline__ float dot2(half2v a, half2v b, float c) {
#if __has_builtin(__builtin_amdgcn_fdot2)
    return __builtin_amdgcn_fdot2(a, b, c, false);     // v_dot2_f32_f16
#else
    return fmaf((float)a.x, (float)b.x, fmaf((float)a.y, (float)b.y, c));
#endif
}

static __device__ __forceinline__ half2v shflxor_h2(half2v x, int m) {
    union { half2v h; int i; } u; u.h = x;
    u.i = __shfl_xor(u.i, m);
    return u.h;
}

// ---------------------------------------------------------------------------
// K_pre v1 (REVERTED from v2): fused projection + CSR offsets.
// v2's strip-split tripled per-output B-fragment setup (+7 us total) —
// k_pre is ~10-15 us, not occupancy-starved enough to matter. Back to the
// known-good 1042-wave config: 3 strips/wave, 8 col-tiles, Bf in VGPRs.
// Blocks [PROJ_BLOCKS, ...): off[n] = lower_bound(dst, n).
// ---------------------------------------------------------------------------
__global__ __launch_bounds__(256, 1) void k_pre(const float* __restrict__ feat,
                                                const float* __restrict__ W,
                                                const int* __restrict__ dst,
                                                _Float16* __restrict__ hb,
                                                int* __restrict__ off) {
    if (blockIdx.x >= PROJ_BLOCKS) {
        int i = (blockIdx.x - PROJ_BLOCKS) * 256 + threadIdx.x;
        if (i <= N_NODES) {
            int lo = 0, hi = N_EDGES;
            while (lo < hi) {
                int mid = (lo + hi) >> 1;
                if (dst[mid] < i) lo = mid + 1; else hi = mid;
            }
            off[i] = lo;
        }
        return;
    }

    int wid = blockIdx.x * 4 + (threadIdx.x >> 6);
    int lane = threadIdx.x & 63;
    int s0 = wid * STRIPS_PER_WAVE;
    if (s0 >= STRIPS) return;
    int quad = lane >> 4;
    int l15 = lane & 15;

    // B fragments: Bf[t][kb] = f16(W[kb*32+quad*8+j][t*16+l15]), j=0..7
    half8 Bf[8][4];
#pragma unroll
    for (int t = 0; t < 8; t++) {
#pragma unroll
        for (int kb = 0; kb < 4; kb++) {
            union { half8 v; half2v h[4]; } bu;
#pragma unroll
            for (int jj = 0; jj < 4; jj++) {
                int k0 = kb * 32 + quad * 8 + 2 * jj;
                float lo = W[(size_t)k0 * HD + t * 16 + l15];
                float hi = W[(size_t)(k0 + 1) * HD + t * 16 + l15];
                bu.h[jj] = pk_f16(lo, hi);
            }
            Bf[t][kb] = bu.v;
        }
    }

    for (int it = 0; it < STRIPS_PER_WAVE; it++) {
        int strip = s0 + it;
        if (strip >= STRIPS) break;
        int row = strip * 16 + l15;

        const float* ab = feat + (size_t)row * IN_SIZE + quad * 8;
        float4 a[8];
#pragma unroll
        for (int kb = 0; kb < 4; kb++) {
            a[2 * kb]     = *(const float4*)(ab + kb * 32);
            a[2 * kb + 1] = *(const float4*)(ab + kb * 32 + 4);
        }

        floatx4 acc[8];
#pragma unroll
        for (int t = 0; t < 8; t++) acc[t] = (floatx4)(0.f);

#pragma unroll
        for (int kb = 0; kb < 4; kb++) {
            float4 x = a[2 * kb], y = a[2 * kb + 1];
            union { half8 v; half2v h[4]; } af;
            af.h[0] = pk_f16(x.x, x.y);
            af.h[1] = pk_f16(x.z, x.w);
            af.h[2] = pk_f16(y.x, y.y);
            af.h[3] = pk_f16(y.z, y.w);
#pragma unroll
            for (int t = 0; t < 8; t++)
                acc[t] = __builtin_amdgcn_mfma_f32_16x16x32_f16(af.v, Bf[t][kb], acc[t], 0, 0, 0);
        }

        // C/D: col = t*16+l15, row = strip*16 + quad*4 + r
#pragma unroll
        for (int t = 0; t < 8; t++) {
#pragma unroll
            for (int r = 0; r < 4; r++) {
                int R = strip * 16 + quad * 4 + r;
                hb[(size_t)R * HD + t * 16 + l15] = (_Float16)acc[t][r];
            }
        }
    }
}

// ---------------------------------------------------------------------------
// K_edge v10: chunk-wide MLP + contiguous-line gathers + reduce-scatter.
// One wave per dst node. Per 64-edge chunk:
//   * ONE coalesced src load (src[cb+lane]) -> indices via ds_bpermute.
//     (kills the dependent src->gather chain; v8 had 8x-redundant loads)
//   * ALL 8 slots' gathers issued before any consume: up to 64 edges
//     (16 KB) in flight per wave (4x v8's 16).
//   * lane p owns row bytes [16p,16p+16) and [128+16p,...): each dwordx4
//     instr covers contiguous 128 B per row = 4 line-touches/row (v8's
//     stride-32 layout touched 8). Lane spans TWO heads (A=p>>2, B=2+A):
//     2-round xor{1,2} quad combine, two exp2/denominators per lane.
//   * Epilogue: reduce-scatter (7 data shuffles vs 27 butterfly); all 64
//     lanes store one float2 of the output row.
// Scalar (wave-uniform) slot guards: m is uniform per wave. No atomics.
// f16 accumulators unchanged (err budget verified at absmax 0.0078).
// ---------------------------------------------------------------------------
__global__ __launch_bounds__(256) void k_edge(const _Float16* __restrict__ hb,
                                              const int* __restrict__ src,
                                              const int* __restrict__ off,
                                              float* __restrict__ out) {
    int n = (blockIdx.x * 256 + threadIdx.x) >> 6;
    int lane = threadIdx.x & 63;
    if (n >= N_NODES) return;
    int e0 = off[n], e1 = off[n + 1];

    int g = lane >> 3;       // edge slot-stream 0..7
    int p = lane & 7;        // byte chunks 16p (dims 8p..8p+7) and 128+16p

    const uint4* h4 = (const uint4*)hb;    // one h row = 16 uint4
    union U { uint4 v[2]; half2v h[8]; };

    // dst row, contiguous-ownership layout
    const uint4* hrow = h4 + (size_t)n * 16;
    U hdv;
    hdv.v[0] = hrow[p];        // f16 elems 8p..8p+7      (head A = p>>2)
    hdv.v[1] = hrow[8 + p];    // f16 elems 64+8p..64+8p+7 (head B = 2+(p>>2))
    half2v hdc[8];
    half2v sc2 = pk_f16(SCALE2, SCALE2);
#pragma unroll
    for (int d = 0; d < 8; d++) hdc[d] = hdv.h[d] * sc2;  // pre-scaled, log2 domain

    float sA = 0.f, sB = 0.f;
    half2v acc2[8];
#pragma unroll
    for (int d = 0; d < 8; d++) acc2[d] = (half2v)(_Float16)0.f;

    for (int cb = e0; cb < e1; cb += 64) {
        int m = e1 - cb;                   // wave-uniform
        if (m > 64) m = 64;
        int li = (lane < m) ? lane : (m - 1);
        int sv = src[cb + li];             // ONE coalesced load covers the chunk

        U v[8];
        // ---- issue phase: all gathers in flight before any consume
#pragma unroll
        for (int k = 0; k < 8; k++) {
            if (8 * k < m) {               // scalar guard (m uniform)
                int idx = __shfl(sv, 8 * k + g);   // ds_bpermute
                const uint4* rp = h4 + (size_t)idx * 16 + p;
                v[k].v[0] = rp[0];         // bytes [16p, 16p+16)
                v[k].v[1] = rp[8];         // bytes [128+16p, ...)
            }
        }
        // ---- consume phase
#pragma unroll
        for (int k = 0; k < 8; k++) {
            if (8 * k < m) {
                bool valid = (8 * k + g) < m;
                // head A partial (dims 8p..8p+7), head B partial (64+8p..)
                float a0 = dot2(v[k].h[0], hdc[0], 0.f);
                float a1 = dot2(v[k].h[1], hdc[1], 0.f);
                float b0 = dot2(v[k].h[4], hdc[4], 0.f);
                float b1 = dot2(v[k].h[5], hdc[5], 0.f);
                a0 = dot2(v[k].h[2], hdc[2], a0);
                a1 = dot2(v[k].h[3], hdc[3], a1);
                b0 = dot2(v[k].h[6], hdc[6], b0);
                b1 = dot2(v[k].h[7], hdc[7], b1);
                float pa = a0 + a1;
                float pb = b0 + b1;
                // quad combine (4 lanes span each head's 32 dims)
                pa += __shfl_xor(pa, 1);
                pb += __shfl_xor(pb, 1);
                pa += __shfl_xor(pa, 2);
                pb += __shfl_xor(pb, 2);
                float wa = valid ? __builtin_amdgcn_exp2f(pa) : 0.f;
                float wb = valid ? __builtin_amdgcn_exp2f(pb) : 0.f;
                sA += wa;
                sB += wb;
                half2v wha = pk_f16(wa, wa);
                half2v whb = pk_f16(wb, wb);
#pragma unroll
                for (int d = 0; d < 4; d++) acc2[d]     += v[k].h[d]     * wha;
#pragma unroll
                for (int d = 0; d < 4; d++) acc2[d + 4] += v[k].h[d + 4] * whb;
            }
        }
    }

    // ---- reduce-scatter over the 8 slot-streams (xor 8, 16, 32) ----
    bool o1 = (g & 1) != 0, o2 = (g & 2) != 0, o4 = (g & 4) != 0;
    half2v r1v[4];
#pragma unroll
    for (int j = 0; j < 4; j++) {
        half2v kp = o1 ? acc2[j + 4] : acc2[j];
        half2v sd = o1 ? acc2[j] : acc2[j + 4];
        r1v[j] = kp + shflxor_h2(sd, 8);
    }
    half2v r2v[2];
#pragma unroll
    for (int j = 0; j < 2; j++) {
        half2v kp = o2 ? r1v[j + 2] : r1v[j];
        half2v sd = o2 ? r1v[j] : r1v[j + 2];
        r2v[j] = kp + shflxor_h2(sd, 16);
    }
    half2v kp3 = o4 ? r2v[1] : r2v[0];
    half2v sd3 = o4 ? r2v[0] : r2v[1];
    half2v fin = kp3 + shflxor_h2(sd3, 32);

    sA += __shfl_xor(sA, 8); sA += __shfl_xor(sA, 16); sA += __shfl_xor(sA, 32);
    sB += __shfl_xor(sB, 8); sB += __shfl_xor(sB, 16); sB += __shfl_xor(sB, 32);
    float invA = (sA > 0.f) ? 1.f / sA : 0.f;
    float invB = (sB > 0.f) ? 1.f / sB : 0.f;
    float inv = o1 ? invB : invA;

    // surviving word w = 4*(g&1) + 2*((g>>1)&1) + ((g>>2)&1);
    // dims: w<4 -> 8p+2w (head A), w>=4 -> 64+8p+2*(w-4) (head B)
    int wlo = ((g >> 1) & 1) * 2 + ((g >> 2) & 1);
    int dim = (o1 ? 64 : 0) + 8 * p + 2 * wlo;
    float2 o;
    o.x = (float)fin.x * inv;
    o.y = (float)fin.y * inv;
    *(float2*)(out + (size_t)n * HD + dim) = o;
}

// ---------------------------------------------------------------------------
extern "C" void kernel_launch(void* const* d_in, const int* in_sizes, int n_in,
                              void* d_out, int out_size, void* d_ws, size_t ws_size,
                              hipStream_t stream) {
    const float* feat = (const float*)d_in[0];
    const int*   src  = (const int*)d_in[1];
    const int*   dst  = (const int*)d_in[2];
    const float* W    = (const float*)d_in[3];
    float* out = (float*)d_out;

    char* ws = (char*)d_ws;
    _Float16* hb = (_Float16*)ws;                      // 12.8 MB, [node][128]
    int* off = (int*)(ws + (size_t)N_NODES * HD * 2);  // ~200 KB

    k_pre<<<PROJ_BLOCKS + OFF_BLOCKS, 256, 0, stream>>>(feat, W, dst, hb, off);
    k_edge<<<(N_NODES + 3) / 4, 256, 0, stream>>>(hb, src, off, out);
}

// Round 4
// 146.321 us; speedup vs baseline: 1.1077x; 1.1077x over previous
//
#include <hip/hip_runtime.h>
#include <math.h>

#define N_NODES 50000
#define N_EDGES 1600000
#define IN_SIZE 128
#define HD 128          // NUM_HEADS * OUT_SIZE
#define NUM_HEADS 4
#define OUT_SIZE 32
#define STRIPS (N_NODES / 16)        // 3125 16-row strips
#define STRIPS_PER_WAVE 3
#define PROJ_WAVES ((STRIPS + STRIPS_PER_WAVE - 1) / STRIPS_PER_WAVE)   // 1042
#define PROJ_BLOCKS ((PROJ_WAVES + 3) / 4)                               // 261
#define OFF_BLOCKS ((N_NODES + 1 + 255) / 256)                           // 196

// 1/sqrt(32) * log2(e): base-2 softmax (exact reformulation)
#define SCALE2 0.25503486f

typedef _Float16 half8 __attribute__((ext_vector_type(8)));
typedef _Float16 half2v __attribute__((ext_vector_type(2)));
typedef __attribute__((ext_vector_type(4))) float floatx4;

static __device__ __forceinline__ half2v pk_f16(float a, float b) {
#if __has_builtin(__builtin_amdgcn_cvt_pkrtz)
    auto r = __builtin_amdgcn_cvt_pkrtz(a, b);         // v_cvt_pkrtz_f16_f32
    union { decltype(r) i; half2v o; } u;
    u.i = r;
    return u.o;
#else
    half2v r; r.x = (_Float16)a; r.y = (_Float16)b; return r;
#endif
}

static __device__ __forceinline__ float dot2(half2v a, half2v b, float c) {
#if __has_builtin(__builtin_amdgcn_fdot2)
    return __builtin_amdgcn_fdot2(a, b, c, false);     // v_dot2_f32_f16
#else
    return fmaf((float)a.x, (float)b.x, fmaf((float)a.y, (float)b.y, c));
#endif
}

static __device__ __forceinline__ half2v shflxor_h2(half2v x, int m) {
    union { half2v h; int i; } u; u.h = x;
    u.i = __shfl_xor(u.i, m);
    return u.h;
}

// ---------------------------------------------------------------------------
// K_pre v1 (known-good): fused projection + CSR offsets.
// 1042 waves, 3 strips/wave, Bf (8x4 half8) in VGPRs, no LDS/barriers.
// Blocks [PROJ_BLOCKS, ...): off[n] = lower_bound(dst, n).
// ---------------------------------------------------------------------------
__global__ __launch_bounds__(256, 1) void k_pre(const float* __restrict__ feat,
                                                const float* __restrict__ W,
                                                const int* __restrict__ dst,
                                                _Float16* __restrict__ hb,
                                                int* __restrict__ off) {
    if (blockIdx.x >= PROJ_BLOCKS) {
        int i = (blockIdx.x - PROJ_BLOCKS) * 256 + threadIdx.x;
        if (i <= N_NODES) {
            int lo = 0, hi = N_EDGES;
            while (lo < hi) {
                int mid = (lo + hi) >> 1;
                if (dst[mid] < i) lo = mid + 1; else hi = mid;
            }
            off[i] = lo;
        }
        return;
    }

    int wid = blockIdx.x * 4 + (threadIdx.x >> 6);
    int lane = threadIdx.x & 63;
    int s0 = wid * STRIPS_PER_WAVE;
    if (s0 >= STRIPS) return;
    int quad = lane >> 4;
    int l15 = lane & 15;

    // B fragments: Bf[t][kb] = f16(W[kb*32+quad*8+j][t*16+l15]), j=0..7
    half8 Bf[8][4];
#pragma unroll
    for (int t = 0; t < 8; t++) {
#pragma unroll
        for (int kb = 0; kb < 4; kb++) {
            union { half8 v; half2v h[4]; } bu;
#pragma unroll
            for (int jj = 0; jj < 4; jj++) {
                int k0 = kb * 32 + quad * 8 + 2 * jj;
                float lo = W[(size_t)k0 * HD + t * 16 + l15];
                float hi = W[(size_t)(k0 + 1) * HD + t * 16 + l15];
                bu.h[jj] = pk_f16(lo, hi);
            }
            Bf[t][kb] = bu.v;
        }
    }

    for (int it = 0; it < STRIPS_PER_WAVE; it++) {
        int strip = s0 + it;
        if (strip >= STRIPS) break;
        int row = strip * 16 + l15;

        const float* ab = feat + (size_t)row * IN_SIZE + quad * 8;
        float4 a[8];
#pragma unroll
        for (int kb = 0; kb < 4; kb++) {
            a[2 * kb]     = *(const float4*)(ab + kb * 32);
            a[2 * kb + 1] = *(const float4*)(ab + kb * 32 + 4);
        }

        floatx4 acc[8];
#pragma unroll
        for (int t = 0; t < 8; t++) acc[t] = (floatx4)(0.f);

#pragma unroll
        for (int kb = 0; kb < 4; kb++) {
            float4 x = a[2 * kb], y = a[2 * kb + 1];
            union { half8 v; half2v h[4]; } af;
            af.h[0] = pk_f16(x.x, x.y);
            af.h[1] = pk_f16(x.z, x.w);
            af.h[2] = pk_f16(y.x, y.y);
            af.h[3] = pk_f16(y.z, y.w);
#pragma unroll
            for (int t = 0; t < 8; t++)
                acc[t] = __builtin_amdgcn_mfma_f32_16x16x32_f16(af.v, Bf[t][kb], acc[t], 0, 0, 0);
        }

        // C/D: col = t*16+l15, row = strip*16 + quad*4 + r
#pragma unroll
        for (int t = 0; t < 8; t++) {
#pragma unroll
            for (int r = 0; r < 4; r++) {
                int R = strip * 16 + quad * 4 + r;
                hb[(size_t)R * HD + t * 16 + l15] = (_Float16)acc[t][r];
            }
        }
    }
}

// ---------------------------------------------------------------------------
// K_edge v11: v8's proven gather idiom + depth-4 quad pipeline + cheap
// reduce-scatter epilogue.
// Layout (= v8): 8 streams (g) x 8 lanes (p); lane owns 32 B [32p,32p+32)
// of the 256 B row = 16 f16 dims of ONE head (h = p>>1).
// Pipeline: prologue issues a full QUAD (4 groups = 32 edges, 8 KB) of
// gathers back-to-back — for the median node (deg~32, Poisson) the ENTIRE
// node is in flight at wave start. Double-buffered quads (va/vb) keep 32
// edges in flight for heavier nodes. All loads UNCONDITIONAL with clamped
// index + select-on-value (v8's idiom — v10 showed guarded array loads get
// sunk by the compiler and the pipeline collapses). No bpermute: per-stream
// src[e] loads (32 distinct, 2 lines per quad — L1/L2-hot).
// Epilogue: reduce-scatter over g (xor 8/16/32; 7 packed-h2 shuffles + 3
// scalar vs v8's 27-shuffle butterfly); lane (g,p) keeps word
// w = 4*(g&1)+2*((g>>1)&1)+((g>>2)&1), stores float2 at dim 16p+2w.
// f16 accumulators unchanged (absmax 0.0078 << budget).
// ---------------------------------------------------------------------------
union U8 { uint4 v[2]; half2v h[8]; };

static __device__ __forceinline__ void loadq(U8 (&d)[4], int qb, int e1, int g, int p, int n,
                                             const int* __restrict__ src,
                                             const uint4* __restrict__ h4) {
#pragma unroll
    for (int j = 0; j < 4; j++) {
        int ee = qb + 8 * j + g;
        bool a = ee < e1;
        int sv = src[a ? ee : 0];          // unconditional load, clamped index
        int row = a ? sv : n;              // select on VALUE (keeps load hoisted)
        const uint4* rp = h4 + (size_t)row * 16 + 2 * p;
        d[j].v[0] = rp[0];                 // bytes [32p, 32p+16)
        d[j].v[1] = rp[1];                 // bytes [32p+16, 32p+32)
    }
}

static __device__ __forceinline__ void procq(const U8 (&vv)[4], int qb, int e1, int g,
                                             const half2v (&hdc)[8], float& s,
                                             half2v (&acc2)[8]) {
#pragma unroll
    for (int j = 0; j < 4; j++) {
        bool valid = (qb + 8 * j + g) < e1;
        float p0 = dot2(vv[j].h[0], hdc[0], 0.f);
        float p1 = dot2(vv[j].h[1], hdc[1], 0.f);
        p0 = dot2(vv[j].h[2], hdc[2], p0);
        p1 = dot2(vv[j].h[3], hdc[3], p1);
        p0 = dot2(vv[j].h[4], hdc[4], p0);
        p1 = dot2(vv[j].h[5], hdc[5], p1);
        p0 = dot2(vv[j].h[6], hdc[6], p0);
        p1 = dot2(vv[j].h[7], hdc[7], p1);
        float pd = p0 + p1;
        pd += __shfl_xor(pd, 1);           // 2 lanes span the head's 32 dims
        float w = valid ? __builtin_amdgcn_exp2f(pd) : 0.f;
        s += w;
        half2v wh = pk_f16(w, w);
#pragma unroll
        for (int d = 0; d < 8; d++) acc2[d] += vv[j].h[d] * wh;   // v_pk_fma_f16
    }
}

__global__ __launch_bounds__(256) void k_edge(const _Float16* __restrict__ hb,
                                              const int* __restrict__ src,
                                              const int* __restrict__ off,
                                              float* __restrict__ out) {
    int n = (blockIdx.x * 256 + threadIdx.x) >> 6;
    int lane = threadIdx.x & 63;
    if (n >= N_NODES) return;
    int e0 = off[n], e1 = off[n + 1];

    int g = lane >> 3;       // edge stream 0..7
    int p = lane & 7;        // dims 16p..16p+15 (head = p>>1)

    const uint4* h4 = (const uint4*)hb;    // one h row = 16 uint4
    const uint4* hrow = h4 + (size_t)n * 16;
    U8 hdv;
    hdv.v[0] = hrow[2 * p];
    hdv.v[1] = hrow[2 * p + 1];
    half2v hdc[8];
    half2v sc2 = pk_f16(SCALE2, SCALE2);
#pragma unroll
    for (int d = 0; d < 8; d++) hdc[d] = hdv.h[d] * sc2;  // pre-scaled, log2 domain

    float s = 0.f;
    half2v acc2[8];
#pragma unroll
    for (int d = 0; d < 8; d++) acc2[d] = (half2v)(_Float16)0.f;

    U8 va[4], vb[4];
    loadq(va, e0, e1, g, p, n, src, h4);   // 32 edges in flight immediately

    int qb = e0;
    while (qb < e1) {
        loadq(vb, qb + 32, e1, g, p, n, src, h4);
        procq(va, qb, e1, g, hdc, s, acc2);
        qb += 32;
        if (qb >= e1) break;
        loadq(va, qb + 32, e1, g, p, n, src, h4);
        procq(vb, qb, e1, g, hdc, s, acc2);
        qb += 32;
    }

    // ---- reduce-scatter over the 8 streams (xor 8, 16, 32) ----
    bool o1 = (g & 1) != 0, o2 = (g & 2) != 0, o4 = (g & 4) != 0;
    half2v r1v[4];
#pragma unroll
    for (int j = 0; j < 4; j++) {
        half2v kp = o1 ? acc2[j + 4] : acc2[j];
        half2v sd = o1 ? acc2[j] : acc2[j + 4];
        r1v[j] = kp + shflxor_h2(sd, 8);
    }
    half2v r2v[2];
#pragma unroll
    for (int j = 0; j < 2; j++) {
        half2v kp = o2 ? r1v[j + 2] : r1v[j];
        half2v sd = o2 ? r1v[j] : r1v[j + 2];
        r2v[j] = kp + shflxor_h2(sd, 16);
    }
    half2v kp3 = o4 ? r2v[1] : r2v[0];
    half2v sd3 = o4 ? r2v[0] : r2v[1];
    half2v fin = kp3 + shflxor_h2(sd3, 32);

    s += __shfl_xor(s, 8); s += __shfl_xor(s, 16); s += __shfl_xor(s, 32);
    float inv = (s > 0.f) ? 1.f / s : 0.f;   // denom for head p>>1 (lane-local)

    // surviving word w: dims (16p+2w, 16p+2w+1) — bijective over g
    int w = 4 * (g & 1) + 2 * ((g >> 1) & 1) + ((g >> 2) & 1);
    int dim = 16 * p + 2 * w;
    float2 o;
    o.x = (float)fin.x * inv;
    o.y = (float)fin.y * inv;
    *(float2*)(out + (size_t)n * HD + dim) = o;
}

// ---------------------------------------------------------------------------
extern "C" void kernel_launch(void* const* d_in, const int* in_sizes, int n_in,
                              void* d_out, int out_size, void* d_ws, size_t ws_size,
                              hipStream_t stream) {
    const float* feat = (const float*)d_in[0];
    const int*   src  = (const int*)d_in[1];
    const int*   dst  = (const int*)d_in[2];
    const float* W    = (const float*)d_in[3];
    float* out = (float*)d_out;

    char* ws = (char*)d_ws;
    _Float16* hb = (_Float16*)ws;                      // 12.8 MB, [node][128]
    int* off = (int*)(ws + (size_t)N_NODES * HD * 2);  // ~200 KB

    k_pre<<<PROJ_BLOCKS + OFF_BLOCKS, 256, 0, stream>>>(feat, W, dst, hb, off);
    k_edge<<<(N_NODES + 3) / 4, 256, 0, stream>>>(hb, src, off, out);
}